// Round 9
// baseline (94.157 us; speedup 1.0000x reference)
//
#include <hip/hip_runtime.h>

#define Bn 16384
#define Tn 2
#define Nn 100
#define BT 4   // batch tiles (of 16 items) per wave in stage1

typedef __attribute__((ext_vector_type(8))) short short8;   // 8 x bf16 MFMA frag
typedef __attribute__((ext_vector_type(4))) float f32x4;    // MFMA accum

__device__ __forceinline__ f32x4 mfma32(short8 a, short8 b, f32x4 c) {
    return __builtin_amdgcn_mfma_f32_16x16x32_bf16(a, b, c, 0, 0, 0);  // R3-verified
}

#define NEG_LOG2E  -1.44269504f
#define NEG_2LOG2E -2.88539008f

__device__ __forceinline__ float frcp(float v) { return __builtin_amdgcn_rcpf(v); }

__device__ __forceinline__ float fexp2(float v) {
#if __has_builtin(__builtin_amdgcn_exp2f)
    return __builtin_amdgcn_exp2f(v);
#else
    float r; asm("v_exp_f32 %0, %1" : "=v"(r) : "v"(v)); return r;
#endif
}
// sigma(c) where c already includes its bias (from the MFMA accumulator)
__device__ __forceinline__ float fsigc(float c) {
    return frcp(1.0f + fexp2(c * NEG_LOG2E));
}
// tanh(u) given s = -2*log2e*u  — clamp-free, no NaN path
__device__ __forceinline__ float ftanh2(float s) {
    return fmaf(frcp(1.0f + fexp2(s)), 2.0f, -1.0f);
}
// legacy forms for stage2 (proven)
__device__ __forceinline__ float fsig(float v) { return frcp(1.0f + __expf(-v)); }
__device__ __forceinline__ float ftanh(float v) {
    v = fminf(fmaxf(v, -15.0f), 15.0f);
    float e = __expf(-2.0f * v);
    return (1.0f - e) * frcp(1.0f + e);
}

// pack 2 f32 -> 2 bf16 (RNE), lo = a, hi = b
__device__ __forceinline__ unsigned pkbf(float a, float b) {
    unsigned r;
    asm("v_cvt_pk_bf16_f32 %0, %1, %2" : "=v"(r) : "v"(a), "v"(b));
    return r;
}

__device__ __forceinline__ short8 mk_frag(unsigned a, unsigned b, unsigned c, unsigned d) {
    union { unsigned u[4]; short8 s; } x;
    x.u[0] = a; x.u[1] = b; x.u[2] = c; x.u[3] = d;
    return x.s;
}

__device__ __forceinline__ unsigned shflu(unsigned v, int src) {
    return (unsigned)__shfl((int)v, src, 64);
}

// Build B-frag for a K=16 operand held in C-layout (R3-verified)
__device__ __forceinline__ short8 buildK16(unsigned hp0, unsigned hp1, int g, int m) {
    int s0 = ((32 * g + m) & 63);
    int s1 = ((32 * g + 16 + m) & 63);
    unsigned r0 = shflu(hp0, s0);
    unsigned r1 = shflu(hp1, s0);
    unsigned r2 = shflu(hp0, s1);
    unsigned r3 = shflu(hp1, s1);
    if (g >= 2) { r0 = 0; r1 = 0; r2 = 0; r3 = 0; }
    return mk_frag(r0, r1, r2, r3);
}

// A-frag for a row-major [16][16] weight: lane row = l&15, k = g*8+jj  (R3-verified)
__device__ __forceinline__ short8 loadA16(const float* __restrict__ w, int g, int jr) {
    if (g < 2) {
        const float4* q = (const float4*)(w + jr * 16 + g * 8);
        float4 q0 = q[0], q1 = q[1];
        return mk_frag(pkbf(q0.x, q0.y), pkbf(q0.z, q0.w),
                       pkbf(q1.x, q1.y), pkbf(q1.z, q1.w));
    }
    return mk_frag(0u, 0u, 0u, 0u);
}

// A-frag for a row-major [16][6] weight (K=6 at k0..5): only group 0 nonzero
__device__ __forceinline__ short8 loadA6(const float* __restrict__ w, int g, int jr) {
    if (g == 0) {
        const float2* q = (const float2*)(w + jr * 6);
        float2 a = q[0], b = q[1], c = q[2];
        return mk_frag(pkbf(a.x, a.y), pkbf(b.x, b.y), pkbf(c.x, c.y), 0u);
    }
    return mk_frag(0u, 0u, 0u, 0u);
}

__device__ __forceinline__ float red4(float part) {
    part += __shfl_xor(part, 16, 64);
    part += __shfl_xor(part, 32, 64);
    return part;
}

// ============================ STAGE 1 (R8 + deferred-MLP dual chain + bias-in-acc) ============================
__global__ __launch_bounds__(256) void stage1_mfma(
    const float* __restrict__ x,
    const float* __restrict__ Wih, const float* __restrict__ Whh,
    const float* __restrict__ bih, const float* __restrict__ bhh,
    const float* __restrict__ Wa1, const float* __restrict__ ba1,
    const float* __restrict__ Wa2, const float* __restrict__ ba2,
    const float* __restrict__ Wa3, const float* __restrict__ ba3,
    float* __restrict__ out0, float* __restrict__ pbuf)
{
    const int n = blockIdx.y;
    const int l = threadIdx.x & 63;
    const int w = threadIdx.x >> 6;
    const int g = l >> 4;
    const int m = l & 15;
    const int wave_base = (blockIdx.x * 4 + w) * (16 * BT);

    short8 Aih0 = loadA6(Wih + n * 288 +  0 * 6, g, m);
    short8 Aih1 = loadA6(Wih + n * 288 + 16 * 6, g, m);
    short8 Aih2 = loadA6(Wih + n * 288 + 32 * 6, g, m);
    short8 Ahh0 = loadA16(Whh + n * 768 +   0, g, m);
    short8 Ahh1 = loadA16(Whh + n * 768 + 256, g, m);
    short8 Ahh2 = loadA16(Whh + n * 768 + 512, g, m);
    short8 Aa1f = loadA16(Wa1 + n * 256, g, m);
    short8 Aa2f = loadA16(Wa2 + n * 256, g, m);

    float4 bi0 = *(const float4*)(bih + n * 48 +  0 + g * 4);
    float4 bi1 = *(const float4*)(bih + n * 48 + 16 + g * 4);
    float4 bi2 = *(const float4*)(bih + n * 48 + 32 + g * 4);
    float4 bh0 = *(const float4*)(bhh + n * 48 +  0 + g * 4);
    float4 bh1 = *(const float4*)(bhh + n * 48 + 16 + g * 4);
    float4 bh2 = *(const float4*)(bhh + n * 48 + 32 + g * 4);
    float4 vb1 = *(const float4*)(ba1 + n * 16 + g * 4);
    float4 vb2 = *(const float4*)(ba2 + n * 16 + g * 4);
    float4 vw3 = *(const float4*)(Wa3 + n * 16 + g * 4);
    const float ba3n = ba3[n];
    const float* bi2a = (const float*)&bi2;
    const float* bh2a = (const float*)&bh2;
    const float* vw3a = (const float*)&vw3;

    // bias accumulators (f32x4) for MFMA C-operand init
    f32x4 BRS, BZS, BI2, BH2, VB1, VB2;
    {
        const float* a = (const float*)&bi0; const float* b = (const float*)&bh0;
        const float* c = (const float*)&bi1; const float* d = (const float*)&bh1;
        const float* e1 = (const float*)&vb1; const float* e2 = (const float*)&vb2;
#pragma unroll
        for (int r = 0; r < 4; ++r) {
            BRS[r] = a[r] + b[r];
            BZS[r] = c[r] + d[r];
            BI2[r] = bi2a[r];
            BH2[r] = bh2a[r];
            VB1[r] = e1[r];
            VB2[r] = e2[r];
        }
    }

    for (int it = 0; it < BT; ++it) {
        const int bb = wave_base + it * 16;

        // dead-tile skip (window [w0,w0+31] mod 200 fully discarded iff w0 <= 57)
        const unsigned w0 = (unsigned)(n * 168 + 2 * bb) % 200u;
        if (w0 <= 57u) continue;

        const float* xr = x + (size_t)(bb + m) * 1200 + n * 6;
        short8 Bx0, Bx1;
        if (g == 0) {
            float2 a  = *(const float2*)xr,        bq = *(const float2*)(xr + 2),
                   a2 = *(const float2*)(xr + 4);
            float2 c  = *(const float2*)(xr + 600), dq = *(const float2*)(xr + 602),
                   c2 = *(const float2*)(xr + 604);
            Bx0 = mk_frag(pkbf(a.x, a.y), pkbf(bq.x, bq.y), pkbf(a2.x, a2.y), 0u);
            Bx1 = mk_frag(pkbf(c.x, c.y), pkbf(dq.x, dq.y), pkbf(c2.x, c2.y), 0u);
        } else { Bx0 = mk_frag(0u,0u,0u,0u); Bx1 = mk_frag(0u,0u,0u,0u); }

        // ---- t = 0 : gates (biases pre-loaded in accumulators) ----
        f32x4 Cr = mfma32(Aih0, Bx0, BRS);
        f32x4 Cz = mfma32(Aih1, Bx0, BZS);
        f32x4 Cn = mfma32(Aih2, Bx0, BI2);
        float h0[4];
#pragma unroll
        for (int r = 0; r < 4; ++r) {
            float rr = fsigc(Cr[r]);
            float zz = fsigc(Cz[r]);
            float s  = fmaf(rr, bh2a[r], Cn[r]) * NEG_2LOG2E;
            float nn = ftanh2(s);
            h0[r] = fmaf(-zz, nn, nn);          // (1-z)*n
        }
        unsigned hp0 = pkbf(h0[0], h0[1]), hp1 = pkbf(h0[2], h0[3]);
        short8 Bh0 = buildK16(hp0, hp1, g, m);

        // ---- t = 1 GRU (MLP-t0 deferred past this point) ----
        f32x4 Cr1 = mfma32(Aih0, Bx1, BRS); Cr1 = mfma32(Ahh0, Bh0, Cr1);
        f32x4 Cz1 = mfma32(Aih1, Bx1, BZS); Cz1 = mfma32(Ahh1, Bh0, Cz1);
        f32x4 Cn1 = mfma32(Aih2, Bx1, BI2);
        f32x4 Cn2 = mfma32(Ahh2, Bh0, BH2);
        float h1[4];
#pragma unroll
        for (int r = 0; r < 4; ++r) {
            float rr = fsigc(Cr1[r]);
            float zz = fsigc(Cz1[r]);
            float s  = fmaf(rr, Cn2[r], Cn1[r]) * NEG_2LOG2E;
            float nn = ftanh2(s);
            h1[r] = fmaf(zz, h0[r] - nn, nn);   // (1-z)*n + z*h0
        }
        short8 Bh1 = buildK16(pkbf(h1[0], h1[1]), pkbf(h1[2], h1[3]), g, m);

        // ---- DUAL MLP: two independent chains (t0 and t1) interleave ----
        f32x4 C1a = mfma32(Aa1f, Bh0, VB1);
        f32x4 C1b = mfma32(Aa1f, Bh1, VB1);
        float a1a[4], a1b[4];
#pragma unroll
        for (int r = 0; r < 4; ++r) {
            a1a[r] = fmaxf(C1a[r], 0.0f);
            a1b[r] = fmaxf(C1b[r], 0.0f);
        }
        short8 Ba1a = buildK16(pkbf(a1a[0], a1a[1]), pkbf(a1a[2], a1a[3]), g, m);
        short8 Ba1b = buildK16(pkbf(a1b[0], a1b[1]), pkbf(a1b[2], a1b[3]), g, m);
        f32x4 C2a = mfma32(Aa2f, Ba1a, VB2);
        f32x4 C2b = mfma32(Aa2f, Ba1b, VB2);
        float pa = 0.0f, pb = 0.0f;
#pragma unroll
        for (int r = 0; r < 4; ++r) {
            pa += fmaxf(C2a[r], 0.0f) * vw3a[r];
            pb += fmaxf(C2b[r], 0.0f) * vw3a[r];
        }
        pa += __shfl_xor(pa, 16, 64); pb += __shfl_xor(pb, 16, 64);
        pa += __shfl_xor(pa, 32, 64); pb += __shfl_xor(pb, 32, 64);
        float o0 = fmaxf(pa + ba3n, 0.0f);
        float o1 = fmaxf(pb + ba3n, 0.0f);

        // ---- scatter through transpose/reshape: a[b,t,n] flat k0=n*B*T+b*T+t ----
        if (g == 0) {
            const unsigned b = (unsigned)(bb + m);
#pragma unroll
            for (int t = 0; t < 2; ++t) {
                unsigned k0 = (unsigned)n * (Bn * Tn) + b * 2u + (unsigned)t;
                unsigned b2 = k0 / 200u;
                unsigned rr = k0 - b2 * 200u;
                unsigned t2 = (rr >= 100u) ? 1u : 0u;
                unsigned n2 = rr - t2 * 100u;
                float v = (t == 0) ? o0 : o1;
                if (t2) out0[b2 * 100u + n2] = v;
                if (n2 == 99u)      pbuf[b2 * 6u + t2 * 3u + 0u] = v;
                else if (n2 == 89u) pbuf[b2 * 6u + t2 * 3u + 1u] = v;
                else if (n2 == 98u) pbuf[b2 * 6u + t2 * 3u + 2u] = v;
            }
        }
    }
}

// ============================ STAGE 2: 8 lanes per item, row-split (R7-proven) ============================
__global__ __launch_bounds__(256) void stage2_split(
    const float* __restrict__ x, const float* __restrict__ pbuf,
    const float* __restrict__ Wl1, const float* __restrict__ bl1,
    const float* __restrict__ Wl2, const float* __restrict__ bl2,
    const float* __restrict__ Wl3, const float* __restrict__ bl3,
    const float* __restrict__ Wihc, const float* __restrict__ Whhc,
    const float* __restrict__ bihc, const float* __restrict__ bhhc,
    const float* __restrict__ Wc1, const float* __restrict__ bc1,
    const float* __restrict__ Wc2, const float* __restrict__ bc2,
    const float* __restrict__ Wc3, const float* __restrict__ bc3,
    float* __restrict__ out1)
{
    const int tid = threadIdx.x;
    const int li  = tid >> 3;          // item in block, 0..31
    const int r   = tid & 7;           // lane role, 0..7
    const int b   = blockIdx.x * 32 + li;

    __shared__ float sf1[32][36];
    __shared__ float shc0[32][16];
    __shared__ float shc1[32][16];
    __shared__ float sv1[32][16];

    float u0[21], u1[21];
    {
        const float* xb = x + (size_t)b * 1200;
#pragma unroll
        for (int t = 0; t < 2; ++t) {
            float* u = t ? u1 : u0;
            const float* xt = xb + t * 600;
            float2 a0 = *(const float2*)(xt + 594), a1 = *(const float2*)(xt + 596),
                   a2 = *(const float2*)(xt + 598);                       // x99
            float2 b0 = *(const float2*)(xt + 534), b1 = *(const float2*)(xt + 536),
                   b2 = *(const float2*)(xt + 538);                       // x89
            float2 c0 = *(const float2*)(xt + 588), c1 = *(const float2*)(xt + 590),
                   c2 = *(const float2*)(xt + 592);                       // x98
            u[0]=a0.x; u[1]=a0.y; u[2]=a1.x; u[3]=a1.y; u[4]=a2.x; u[5]=a2.y;
            u[6]  = pbuf[b * 6 + t * 3 + 0];
            u[7]=b0.x; u[8]=b0.y; u[9]=b1.x; u[10]=b1.y; u[11]=b2.x; u[12]=b2.y;
            u[13] = pbuf[b * 6 + t * 3 + 1];
            u[14]=c0.x; u[15]=c0.y; u[16]=c1.x; u[17]=c1.y; u[18]=c2.x; u[19]=c2.y;
            u[20] = pbuf[b * 6 + t * 3 + 2];
        }
    }
    const int cmap[21] = {0,1,2,3,4,5,6, 7,8,9,10,11,12,13, 28,29,30,31,32,33,34};

#pragma unroll
    for (int k = 0; k < 5; ++k) {
        int j = r + 8 * k;
        if (j < 35) {
            const float* row = Wl1 + j * 35;
            float acc = bl1[j];
#pragma unroll
            for (int c = 0; c < 21; ++c) acc = fmaf(u1[c], row[cmap[c]], acc);
            sf1[li][j] = fmaxf(acc, 0.0f);
        }
    }
    __syncthreads();
    float f1[35];
    {
        const float4* p4 = (const float4*)&sf1[li][0];
#pragma unroll
        for (int q = 0; q < 8; ++q) {
            float4 v = p4[q];
            f1[4*q]=v.x; f1[4*q+1]=v.y; f1[4*q+2]=v.z; f1[4*q+3]=v.w;
        }
        f1[32]=sf1[li][32]; f1[33]=sf1[li][33]; f1[34]=sf1[li][34];
    }

    float fvp = 0.0f;
#pragma unroll
    for (int k = 0; k < 5; ++k) {
        int j = r + 8 * k;
        if (j < 35) {
            const float* row = Wl2 + j * 35;
            float acc = bl2[j];
#pragma unroll
            for (int kk = 0; kk < 35; ++kk) acc = fmaf(f1[kk], row[kk], acc);
            fvp += fmaxf(acc, 0.0f) * Wl3[j];
        }
    }
    fvp += __shfl_xor(fvp, 1, 64);
    fvp += __shfl_xor(fvp, 2, 64);
    fvp += __shfl_xor(fvp, 4, 64);
    const float fv = fmaxf(fvp + bl3[0], 0.0f);

    float g0[6], g1[6];
#pragma unroll
    for (int k = 0; k < 6; ++k) {
        int j = r + 8 * k;
        const float* row = Wihc + j * 35;
        float a0 = bihc[j], a1 = a0;
#pragma unroll
        for (int c = 0; c < 21; ++c) {
            float wv = row[cmap[c]];
            a0 = fmaf(u0[c], wv, a0);
            a1 = fmaf(u1[c], wv, a1);
        }
        g0[k] = a0; g1[k] = a1;
    }

    float bhr0 = bhhc[r],     bhz0 = bhhc[16 + r],  bhn0 = bhhc[32 + r];
    float bhr1 = bhhc[8 + r], bhz1 = bhhc[24 + r],  bhn1 = bhhc[40 + r];
    {
        float rr = fsig(g0[0] + bhr0);
        float zz = fsig(g0[2] + bhz0);
        float nn = ftanh(g0[4] + rr * bhn0);
        shc0[li][r] = (1.0f - zz) * nn;
        float rr2 = fsig(g0[1] + bhr1);
        float zz2 = fsig(g0[3] + bhz1);
        float nn2 = ftanh(g0[5] + rr2 * bhn1);
        shc0[li][r + 8] = (1.0f - zz2) * nn2;
    }
    __syncthreads();
    float hc0f[16];
    {
        const float4* p4 = (const float4*)&shc0[li][0];
#pragma unroll
        for (int q = 0; q < 4; ++q) {
            float4 v = p4[q];
            hc0f[4*q]=v.x; hc0f[4*q+1]=v.y; hc0f[4*q+2]=v.z; hc0f[4*q+3]=v.w;
        }
    }

    float gh[6];
#pragma unroll
    for (int k = 0; k < 6; ++k) {
        int j = r + 8 * k;
        const float4* wr = (const float4*)(Whhc + j * 16);
        float acc = bhhc[j];
#pragma unroll
        for (int q = 0; q < 4; ++q) {
            float4 v = wr[q];
            acc = fmaf(hc0f[4*q], v.x, acc);   acc = fmaf(hc0f[4*q+1], v.y, acc);
            acc = fmaf(hc0f[4*q+2], v.z, acc); acc = fmaf(hc0f[4*q+3], v.w, acc);
        }
        gh[k] = acc;
    }

    {
        float rr = fsig(g1[0] + gh[0]);
        float zz = fsig(g1[2] + gh[2]);
        float nn = ftanh(g1[4] + rr * gh[4]);
        shc1[li][r] = (1.0f - zz) * nn + zz * hc0f[r];
        float rr2 = fsig(g1[1] + gh[1]);
        float zz2 = fsig(g1[3] + gh[3]);
        float nn2 = ftanh(g1[5] + rr2 * gh[5]);
        shc1[li][r + 8] = (1.0f - zz2) * nn2 + zz2 * hc0f[r + 8];
    }
    __syncthreads();
    float hc1f[16];
    {
        const float4* p4 = (const float4*)&shc1[li][0];
#pragma unroll
        for (int q = 0; q < 4; ++q) {
            float4 v = p4[q];
            hc1f[4*q]=v.x; hc1f[4*q+1]=v.y; hc1f[4*q+2]=v.z; hc1f[4*q+3]=v.w;
        }
    }

#pragma unroll
    for (int k = 0; k < 2; ++k) {
        int j = r + 8 * k;
        const float4* wr = (const float4*)(Wc1 + j * 16);
        float acc = bc1[j];
#pragma unroll
        for (int q = 0; q < 4; ++q) {
            float4 v = wr[q];
            acc = fmaf(hc1f[4*q], v.x, acc);   acc = fmaf(hc1f[4*q+1], v.y, acc);
            acc = fmaf(hc1f[4*q+2], v.z, acc); acc = fmaf(hc1f[4*q+3], v.w, acc);
        }
        sv1[li][j] = fmaxf(acc, 0.0f);
    }
    __syncthreads();
    float v1f[16];
    {
        const float4* p4 = (const float4*)&sv1[li][0];
#pragma unroll
        for (int q = 0; q < 4; ++q) {
            float4 v = p4[q];
            v1f[4*q]=v.x; v1f[4*q+1]=v.y; v1f[4*q+2]=v.z; v1f[4*q+3]=v.w;
        }
    }

    float qvp = 0.0f;
#pragma unroll
    for (int k = 0; k < 2; ++k) {
        int j = r + 8 * k;
        const float4* wr = (const float4*)(Wc2 + j * 16);
        float acc = bc2[j];
#pragma unroll
        for (int q = 0; q < 4; ++q) {
            float4 v = wr[q];
            acc = fmaf(v1f[4*q], v.x, acc);   acc = fmaf(v1f[4*q+1], v.y, acc);
            acc = fmaf(v1f[4*q+2], v.z, acc); acc = fmaf(v1f[4*q+3], v.w, acc);
        }
        qvp += fmaxf(acc, 0.0f) * Wc3[j];
    }
    qvp += __shfl_xor(qvp, 1, 64);
    qvp += __shfl_xor(qvp, 2, 64);
    qvp += __shfl_xor(qvp, 4, 64);
    const float qv = fmaxf(qvp + bc3[0], 0.0f);

    if (r == 0) out1[b] = fv + qv;
}

extern "C" void kernel_launch(void* const* d_in, const int* in_sizes, int n_in,
                              void* d_out, int out_size, void* d_ws, size_t ws_size,
                              hipStream_t stream)
{
    const float* x    = (const float*)d_in[0];
    const float* Wih  = (const float*)d_in[1];
    const float* Whh  = (const float*)d_in[2];
    const float* bih  = (const float*)d_in[3];
    const float* bhh  = (const float*)d_in[4];
    const float* Wa1  = (const float*)d_in[5];
    const float* ba1  = (const float*)d_in[6];
    const float* Wa2  = (const float*)d_in[7];
    const float* ba2  = (const float*)d_in[8];
    const float* Wa3  = (const float*)d_in[9];
    const float* ba3  = (const float*)d_in[10];
    const float* Wl1  = (const float*)d_in[11];
    const float* bl1  = (const float*)d_in[12];
    const float* Wl2  = (const float*)d_in[13];
    const float* bl2  = (const float*)d_in[14];
    const float* Wl3  = (const float*)d_in[15];
    const float* bl3  = (const float*)d_in[16];
    const float* Wihc = (const float*)d_in[17];
    const float* Whhc = (const float*)d_in[18];
    const float* bihc = (const float*)d_in[19];
    const float* bhhc = (const float*)d_in[20];
    const float* Wc1  = (const float*)d_in[21];
    const float* bc1  = (const float*)d_in[22];
    const float* Wc2  = (const float*)d_in[23];
    const float* bc2  = (const float*)d_in[24];
    const float* Wc3  = (const float*)d_in[25];
    const float* bc3  = (const float*)d_in[26];

    float* out0 = (float*)d_out;                    // p[:, -1, :]  (B*N)
    float* out1 = out0 + (size_t)Bn * Nn;           // q            (B)
    float* pbuf = (float*)d_ws;                     // B*6 floats

    dim3 g1(Bn / (16 * 4 * BT), Nn);                // 64 x 100 blocks, 4 waves each
    stage1_mfma<<<g1, 256, 0, stream>>>(x, Wih, Whh, bih, bhh,
                                        Wa1, ba1, Wa2, ba2, Wa3, ba3,
                                        out0, pbuf);
    stage2_split<<<Bn / 32, 256, 0, stream>>>(x, pbuf,
                                              Wl1, bl1, Wl2, bl2, Wl3, bl3,
                                              Wihc, Whhc, bihc, bhhc,
                                              Wc1, bc1, Wc2, bc2, Wc3, bc3,
                                              out1);
}

// Round 10
// 92.511 us; speedup vs baseline: 1.0178x; 1.0178x over previous
//
#include <hip/hip_runtime.h>

#define Bn 16384
#define Tn 2
#define Nn 100
#define BT 4   // batch tiles (of 16 items) per wave in stage1

typedef __attribute__((ext_vector_type(8))) short short8;   // 8 x bf16 MFMA frag
typedef __attribute__((ext_vector_type(4))) float f32x4;    // MFMA accum

__device__ __forceinline__ f32x4 mfma32(short8 a, short8 b, f32x4 c) {
    return __builtin_amdgcn_mfma_f32_16x16x32_bf16(a, b, c, 0, 0, 0);  // R3-verified
}

#define NEG_LOG2E  -1.44269504f
#define NEG_2LOG2E -2.88539008f

__device__ __forceinline__ float frcp(float v) { return __builtin_amdgcn_rcpf(v); }

__device__ __forceinline__ float fexp2(float v) {
#if __has_builtin(__builtin_amdgcn_exp2f)
    return __builtin_amdgcn_exp2f(v);
#else
    float r; asm("v_exp_f32 %0, %1" : "=v"(r) : "v"(v)); return r;
#endif
}
// sigma(c) where c already includes its bias (from the MFMA accumulator)
__device__ __forceinline__ float fsigc(float c) {
    return frcp(1.0f + fexp2(c * NEG_LOG2E));
}
// tanh(u) given s = -2*log2e*u  — clamp-free, no NaN path
__device__ __forceinline__ float ftanh2(float s) {
    return fmaf(frcp(1.0f + fexp2(s)), 2.0f, -1.0f);
}
// legacy forms for stage2 (proven)
__device__ __forceinline__ float fsig(float v) { return frcp(1.0f + __expf(-v)); }
__device__ __forceinline__ float ftanh(float v) {
    v = fminf(fmaxf(v, -15.0f), 15.0f);
    float e = __expf(-2.0f * v);
    return (1.0f - e) * frcp(1.0f + e);
}

// pack 2 f32 -> 2 bf16 (RNE), lo = a, hi = b
__device__ __forceinline__ unsigned pkbf(float a, float b) {
    unsigned r;
    asm("v_cvt_pk_bf16_f32 %0, %1, %2" : "=v"(r) : "v"(a), "v"(b));
    return r;
}

__device__ __forceinline__ short8 mk_frag(unsigned a, unsigned b, unsigned c, unsigned d) {
    union { unsigned u[4]; short8 s; } x;
    x.u[0] = a; x.u[1] = b; x.u[2] = c; x.u[3] = d;
    return x.s;
}

__device__ __forceinline__ unsigned shflu(unsigned v, int src) {
    return (unsigned)__shfl((int)v, src, 64);
}

// Build B-frag for a K=16 operand held in C-layout (R3-verified)
__device__ __forceinline__ short8 buildK16(unsigned hp0, unsigned hp1, int g, int m) {
    int s0 = ((32 * g + m) & 63);
    int s1 = ((32 * g + 16 + m) & 63);
    unsigned r0 = shflu(hp0, s0);
    unsigned r1 = shflu(hp1, s0);
    unsigned r2 = shflu(hp0, s1);
    unsigned r3 = shflu(hp1, s1);
    if (g >= 2) { r0 = 0; r1 = 0; r2 = 0; r3 = 0; }
    return mk_frag(r0, r1, r2, r3);
}

// A-frag for a row-major [16][16] weight: lane row = l&15, k = g*8+jj  (R3-verified)
__device__ __forceinline__ short8 loadA16(const float* __restrict__ w, int g, int jr) {
    if (g < 2) {
        const float4* q = (const float4*)(w + jr * 16 + g * 8);
        float4 q0 = q[0], q1 = q[1];
        return mk_frag(pkbf(q0.x, q0.y), pkbf(q0.z, q0.w),
                       pkbf(q1.x, q1.y), pkbf(q1.z, q1.w));
    }
    return mk_frag(0u, 0u, 0u, 0u);
}

// A-frag for a row-major [16][6] weight (K=6 at k0..5): only group 0 nonzero
__device__ __forceinline__ short8 loadA6(const float* __restrict__ w, int g, int jr) {
    if (g == 0) {
        const float2* q = (const float2*)(w + jr * 6);
        float2 a = q[0], b = q[1], c = q[2];
        return mk_frag(pkbf(a.x, a.y), pkbf(b.x, b.y), pkbf(c.x, c.y), 0u);
    }
    return mk_frag(0u, 0u, 0u, 0u);
}

// ============================ STAGE 1 (R9 + x prefetch-1 pipeline) ============================
__global__ __launch_bounds__(256) void stage1_mfma(
    const float* __restrict__ x,
    const float* __restrict__ Wih, const float* __restrict__ Whh,
    const float* __restrict__ bih, const float* __restrict__ bhh,
    const float* __restrict__ Wa1, const float* __restrict__ ba1,
    const float* __restrict__ Wa2, const float* __restrict__ ba2,
    const float* __restrict__ Wa3, const float* __restrict__ ba3,
    float* __restrict__ out0, float* __restrict__ pbuf)
{
    const int n = blockIdx.y;
    const int l = threadIdx.x & 63;
    const int w = threadIdx.x >> 6;
    const int g = l >> 4;
    const int m = l & 15;
    const int wave_base = (blockIdx.x * 4 + w) * (16 * BT);

    short8 Aih0 = loadA6(Wih + n * 288 +  0 * 6, g, m);
    short8 Aih1 = loadA6(Wih + n * 288 + 16 * 6, g, m);
    short8 Aih2 = loadA6(Wih + n * 288 + 32 * 6, g, m);
    short8 Ahh0 = loadA16(Whh + n * 768 +   0, g, m);
    short8 Ahh1 = loadA16(Whh + n * 768 + 256, g, m);
    short8 Ahh2 = loadA16(Whh + n * 768 + 512, g, m);
    short8 Aa1f = loadA16(Wa1 + n * 256, g, m);
    short8 Aa2f = loadA16(Wa2 + n * 256, g, m);

    float4 bi0 = *(const float4*)(bih + n * 48 +  0 + g * 4);
    float4 bi1 = *(const float4*)(bih + n * 48 + 16 + g * 4);
    float4 bi2 = *(const float4*)(bih + n * 48 + 32 + g * 4);
    float4 bh0 = *(const float4*)(bhh + n * 48 +  0 + g * 4);
    float4 bh1 = *(const float4*)(bhh + n * 48 + 16 + g * 4);
    float4 bh2 = *(const float4*)(bhh + n * 48 + 32 + g * 4);
    float4 vb1 = *(const float4*)(ba1 + n * 16 + g * 4);
    float4 vb2 = *(const float4*)(ba2 + n * 16 + g * 4);
    float4 vw3 = *(const float4*)(Wa3 + n * 16 + g * 4);
    const float ba3n = ba3[n];
    const float* bh2a = (const float*)&bh2;
    const float* vw3a = (const float*)&vw3;

    // bias accumulators (f32x4) for MFMA C-operand init
    f32x4 BRS, BZS, BI2, BH2, VB1, VB2;
    {
        const float* a = (const float*)&bi0; const float* b = (const float*)&bh0;
        const float* c = (const float*)&bi1; const float* d = (const float*)&bh1;
        const float* e0 = (const float*)&bi2;
        const float* e1 = (const float*)&vb1; const float* e2 = (const float*)&vb2;
#pragma unroll
        for (int r = 0; r < 4; ++r) {
            BRS[r] = a[r] + b[r];
            BZS[r] = c[r] + d[r];
            BI2[r] = e0[r];
            BH2[r] = bh2a[r];
            VB1[r] = e1[r];
            VB2[r] = e2[r];
        }
    }

    // ---- x prefetch registers (tile 'it'); issued one tile ahead ----
    float2 p0, p1, p2, p3, p4, p5;
#define LOADX(BB) do { if (g == 0) { \
        const float* xr_ = x + (size_t)((BB) + m) * 1200 + n * 6; \
        p0 = *(const float2*)(xr_);       p1 = *(const float2*)(xr_ + 2); \
        p2 = *(const float2*)(xr_ + 4);   p3 = *(const float2*)(xr_ + 600); \
        p4 = *(const float2*)(xr_ + 602); p5 = *(const float2*)(xr_ + 604); } } while (0)

    LOADX(wave_base);   // tile 0

    for (int it = 0; it < BT; ++it) {
        const int bb = wave_base + it * 16;

        // dead-tile test (window [w0,w0+31] mod 200 fully discarded iff w0 <= 57)
        const unsigned w0 = (unsigned)(n * 168 + 2 * bb) % 200u;
        const bool live = (w0 > 57u);

        // pack current tile's x from prefetch regs (before they're overwritten)
        short8 Bx0 = mk_frag(0u,0u,0u,0u), Bx1 = mk_frag(0u,0u,0u,0u);
        if (live && g == 0) {
            Bx0 = mk_frag(pkbf(p0.x, p0.y), pkbf(p1.x, p1.y), pkbf(p2.x, p2.y), 0u);
            Bx1 = mk_frag(pkbf(p3.x, p3.y), pkbf(p4.x, p4.y), pkbf(p5.x, p5.y), 0u);
        }
        // issue next tile's loads; latency hides under this tile's body
        if (it + 1 < BT) LOADX(bb + 16);
        if (!live) continue;

        // ---- t0 gi MFMAs, then h-independent t1 gi MFMAs (fill matrix pipe) ----
        f32x4 Cr  = mfma32(Aih0, Bx0, BRS);
        f32x4 Cz  = mfma32(Aih1, Bx0, BZS);
        f32x4 Cn  = mfma32(Aih2, Bx0, BI2);
        f32x4 Cr1 = mfma32(Aih0, Bx1, BRS);
        f32x4 Cz1 = mfma32(Aih1, Bx1, BZS);
        f32x4 Cn1 = mfma32(Aih2, Bx1, BI2);

        // ---- t0 gates ----
        float h0[4];
#pragma unroll
        for (int r = 0; r < 4; ++r) {
            float rr = fsigc(Cr[r]);
            float zz = fsigc(Cz[r]);
            float s  = fmaf(rr, bh2a[r], Cn[r]) * NEG_2LOG2E;
            float nn = ftanh2(s);
            h0[r] = fmaf(-zz, nn, nn);          // (1-z)*n
        }
        unsigned hp0 = pkbf(h0[0], h0[1]), hp1 = pkbf(h0[2], h0[3]);
        short8 Bh0 = buildK16(hp0, hp1, g, m);

        // ---- t1 hidden-path MFMAs + t0 MLP layer-1 (independent of t1 gates) ----
        Cr1 = mfma32(Ahh0, Bh0, Cr1);
        Cz1 = mfma32(Ahh1, Bh0, Cz1);
        f32x4 Cn2 = mfma32(Ahh2, Bh0, BH2);
        f32x4 C1a = mfma32(Aa1f, Bh0, VB1);

        // ---- t1 gates ----
        float h1[4];
#pragma unroll
        for (int r = 0; r < 4; ++r) {
            float rr = fsigc(Cr1[r]);
            float zz = fsigc(Cz1[r]);
            float s  = fmaf(rr, Cn2[r], Cn1[r]) * NEG_2LOG2E;
            float nn = ftanh2(s);
            h1[r] = fmaf(zz, h0[r] - nn, nn);   // (1-z)*n + z*h0
        }
        short8 Bh1 = buildK16(pkbf(h1[0], h1[1]), pkbf(h1[2], h1[3]), g, m);

        // ---- DUAL MLP tail: two independent chains interleave ----
        f32x4 C1b = mfma32(Aa1f, Bh1, VB1);
        float a1a[4], a1b[4];
#pragma unroll
        for (int r = 0; r < 4; ++r) {
            a1a[r] = fmaxf(C1a[r], 0.0f);
            a1b[r] = fmaxf(C1b[r], 0.0f);
        }
        short8 Ba1a = buildK16(pkbf(a1a[0], a1a[1]), pkbf(a1a[2], a1a[3]), g, m);
        short8 Ba1b = buildK16(pkbf(a1b[0], a1b[1]), pkbf(a1b[2], a1b[3]), g, m);
        f32x4 C2a = mfma32(Aa2f, Ba1a, VB2);
        f32x4 C2b = mfma32(Aa2f, Ba1b, VB2);
        float pa = 0.0f, pb = 0.0f;
#pragma unroll
        for (int r = 0; r < 4; ++r) {
            pa += fmaxf(C2a[r], 0.0f) * vw3a[r];
            pb += fmaxf(C2b[r], 0.0f) * vw3a[r];
        }
        pa += __shfl_xor(pa, 16, 64); pb += __shfl_xor(pb, 16, 64);
        pa += __shfl_xor(pa, 32, 64); pb += __shfl_xor(pb, 32, 64);
        float o0 = fmaxf(pa + ba3n, 0.0f);
        float o1 = fmaxf(pb + ba3n, 0.0f);

        // ---- scatter through transpose/reshape: a[b,t,n] flat k0=n*B*T+b*T+t ----
        if (g == 0) {
            const unsigned b = (unsigned)(bb + m);
#pragma unroll
            for (int t = 0; t < 2; ++t) {
                unsigned k0 = (unsigned)n * (Bn * Tn) + b * 2u + (unsigned)t;
                unsigned b2 = k0 / 200u;
                unsigned rr = k0 - b2 * 200u;
                unsigned t2 = (rr >= 100u) ? 1u : 0u;
                unsigned n2 = rr - t2 * 100u;
                float v = (t == 0) ? o0 : o1;
                if (t2) out0[b2 * 100u + n2] = v;
                if (n2 == 99u)      pbuf[b2 * 6u + t2 * 3u + 0u] = v;
                else if (n2 == 89u) pbuf[b2 * 6u + t2 * 3u + 1u] = v;
                else if (n2 == 98u) pbuf[b2 * 6u + t2 * 3u + 2u] = v;
            }
        }
    }
#undef LOADX
}

// ============================ STAGE 2: 8 lanes per item, row-split (R7-proven) ============================
__global__ __launch_bounds__(256) void stage2_split(
    const float* __restrict__ x, const float* __restrict__ pbuf,
    const float* __restrict__ Wl1, const float* __restrict__ bl1,
    const float* __restrict__ Wl2, const float* __restrict__ bl2,
    const float* __restrict__ Wl3, const float* __restrict__ bl3,
    const float* __restrict__ Wihc, const float* __restrict__ Whhc,
    const float* __restrict__ bihc, const float* __restrict__ bhhc,
    const float* __restrict__ Wc1, const float* __restrict__ bc1,
    const float* __restrict__ Wc2, const float* __restrict__ bc2,
    const float* __restrict__ Wc3, const float* __restrict__ bc3,
    float* __restrict__ out1)
{
    const int tid = threadIdx.x;
    const int li  = tid >> 3;          // item in block, 0..31
    const int r   = tid & 7;           // lane role, 0..7
    const int b   = blockIdx.x * 32 + li;

    __shared__ float sf1[32][36];
    __shared__ float shc0[32][16];
    __shared__ float shc1[32][16];
    __shared__ float sv1[32][16];

    float u0[21], u1[21];
    {
        const float* xb = x + (size_t)b * 1200;
#pragma unroll
        for (int t = 0; t < 2; ++t) {
            float* u = t ? u1 : u0;
            const float* xt = xb + t * 600;
            float2 a0 = *(const float2*)(xt + 594), a1 = *(const float2*)(xt + 596),
                   a2 = *(const float2*)(xt + 598);                       // x99
            float2 b0 = *(const float2*)(xt + 534), b1 = *(const float2*)(xt + 536),
                   b2 = *(const float2*)(xt + 538);                       // x89
            float2 c0 = *(const float2*)(xt + 588), c1 = *(const float2*)(xt + 590),
                   c2 = *(const float2*)(xt + 592);                       // x98
            u[0]=a0.x; u[1]=a0.y; u[2]=a1.x; u[3]=a1.y; u[4]=a2.x; u[5]=a2.y;
            u[6]  = pbuf[b * 6 + t * 3 + 0];
            u[7]=b0.x; u[8]=b0.y; u[9]=b1.x; u[10]=b1.y; u[11]=b2.x; u[12]=b2.y;
            u[13] = pbuf[b * 6 + t * 3 + 1];
            u[14]=c0.x; u[15]=c0.y; u[16]=c1.x; u[17]=c1.y; u[18]=c2.x; u[19]=c2.y;
            u[20] = pbuf[b * 6 + t * 3 + 2];
        }
    }
    const int cmap[21] = {0,1,2,3,4,5,6, 7,8,9,10,11,12,13, 28,29,30,31,32,33,34};

#pragma unroll
    for (int k = 0; k < 5; ++k) {
        int j = r + 8 * k;
        if (j < 35) {
            const float* row = Wl1 + j * 35;
            float acc = bl1[j];
#pragma unroll
            for (int c = 0; c < 21; ++c) acc = fmaf(u1[c], row[cmap[c]], acc);
            sf1[li][j] = fmaxf(acc, 0.0f);
        }
    }
    __syncthreads();
    float f1[35];
    {
        const float4* p4 = (const float4*)&sf1[li][0];
#pragma unroll
        for (int q = 0; q < 8; ++q) {
            float4 v = p4[q];
            f1[4*q]=v.x; f1[4*q+1]=v.y; f1[4*q+2]=v.z; f1[4*q+3]=v.w;
        }
        f1[32]=sf1[li][32]; f1[33]=sf1[li][33]; f1[34]=sf1[li][34];
    }

    float fvp = 0.0f;
#pragma unroll
    for (int k = 0; k < 5; ++k) {
        int j = r + 8 * k;
        if (j < 35) {
            const float* row = Wl2 + j * 35;
            float acc = bl2[j];
#pragma unroll
            for (int kk = 0; kk < 35; ++kk) acc = fmaf(f1[kk], row[kk], acc);
            fvp += fmaxf(acc, 0.0f) * Wl3[j];
        }
    }
    fvp += __shfl_xor(fvp, 1, 64);
    fvp += __shfl_xor(fvp, 2, 64);
    fvp += __shfl_xor(fvp, 4, 64);
    const float fv = fmaxf(fvp + bl3[0], 0.0f);

    float g0[6], g1[6];
#pragma unroll
    for (int k = 0; k < 6; ++k) {
        int j = r + 8 * k;
        const float* row = Wihc + j * 35;
        float a0 = bihc[j], a1 = a0;
#pragma unroll
        for (int c = 0; c < 21; ++c) {
            float wv = row[cmap[c]];
            a0 = fmaf(u0[c], wv, a0);
            a1 = fmaf(u1[c], wv, a1);
        }
        g0[k] = a0; g1[k] = a1;
    }

    float bhr0 = bhhc[r],     bhz0 = bhhc[16 + r],  bhn0 = bhhc[32 + r];
    float bhr1 = bhhc[8 + r], bhz1 = bhhc[24 + r],  bhn1 = bhhc[40 + r];
    {
        float rr = fsig(g0[0] + bhr0);
        float zz = fsig(g0[2] + bhz0);
        float nn = ftanh(g0[4] + rr * bhn0);
        shc0[li][r] = (1.0f - zz) * nn;
        float rr2 = fsig(g0[1] + bhr1);
        float zz2 = fsig(g0[3] + bhz1);
        float nn2 = ftanh(g0[5] + rr2 * bhn1);
        shc0[li][r + 8] = (1.0f - zz2) * nn2;
    }
    __syncthreads();
    float hc0f[16];
    {
        const float4* p4 = (const float4*)&shc0[li][0];
#pragma unroll
        for (int q = 0; q < 4; ++q) {
            float4 v = p4[q];
            hc0f[4*q]=v.x; hc0f[4*q+1]=v.y; hc0f[4*q+2]=v.z; hc0f[4*q+3]=v.w;
        }
    }

    float gh[6];
#pragma unroll
    for (int k = 0; k < 6; ++k) {
        int j = r + 8 * k;
        const float4* wr = (const float4*)(Whhc + j * 16);
        float acc = bhhc[j];
#pragma unroll
        for (int q = 0; q < 4; ++q) {
            float4 v = wr[q];
            acc = fmaf(hc0f[4*q], v.x, acc);   acc = fmaf(hc0f[4*q+1], v.y, acc);
            acc = fmaf(hc0f[4*q+2], v.z, acc); acc = fmaf(hc0f[4*q+3], v.w, acc);
        }
        gh[k] = acc;
    }

    {
        float rr = fsig(g1[0] + gh[0]);
        float zz = fsig(g1[2] + gh[2]);
        float nn = ftanh(g1[4] + rr * gh[4]);
        shc1[li][r] = (1.0f - zz) * nn + zz * hc0f[r];
        float rr2 = fsig(g1[1] + gh[1]);
        float zz2 = fsig(g1[3] + gh[3]);
        float nn2 = ftanh(g1[5] + rr2 * gh[5]);
        shc1[li][r + 8] = (1.0f - zz2) * nn2 + zz2 * hc0f[r + 8];
    }
    __syncthreads();
    float hc1f[16];
    {
        const float4* p4 = (const float4*)&shc1[li][0];
#pragma unroll
        for (int q = 0; q < 4; ++q) {
            float4 v = p4[q];
            hc1f[4*q]=v.x; hc1f[4*q+1]=v.y; hc1f[4*q+2]=v.z; hc1f[4*q+3]=v.w;
        }
    }

#pragma unroll
    for (int k = 0; k < 2; ++k) {
        int j = r + 8 * k;
        const float4* wr = (const float4*)(Wc1 + j * 16);
        float acc = bc1[j];
#pragma unroll
        for (int q = 0; q < 4; ++q) {
            float4 v = wr[q];
            acc = fmaf(hc1f[4*q], v.x, acc);   acc = fmaf(hc1f[4*q+1], v.y, acc);
            acc = fmaf(hc1f[4*q+2], v.z, acc); acc = fmaf(hc1f[4*q+3], v.w, acc);
        }
        sv1[li][j] = fmaxf(acc, 0.0f);
    }
    __syncthreads();
    float v1f[16];
    {
        const float4* p4 = (const float4*)&sv1[li][0];
#pragma unroll
        for (int q = 0; q < 4; ++q) {
            float4 v = p4[q];
            v1f[4*q]=v.x; v1f[4*q+1]=v.y; v1f[4*q+2]=v.z; v1f[4*q+3]=v.w;
        }
    }

    float qvp = 0.0f;
#pragma unroll
    for (int k = 0; k < 2; ++k) {
        int j = r + 8 * k;
        const float4* wr = (const float4*)(Wc2 + j * 16);
        float acc = bc2[j];
#pragma unroll
        for (int q = 0; q < 4; ++q) {
            float4 v = wr[q];
            acc = fmaf(v1f[4*q], v.x, acc);   acc = fmaf(v1f[4*q+1], v.y, acc);
            acc = fmaf(v1f[4*q+2], v.z, acc); acc = fmaf(v1f[4*q+3], v.w, acc);
        }
        qvp += fmaxf(acc, 0.0f) * Wc3[j];
    }
    qvp += __shfl_xor(qvp, 1, 64);
    qvp += __shfl_xor(qvp, 2, 64);
    qvp += __shfl_xor(qvp, 4, 64);
    const float qv = fmaxf(qvp + bc3[0], 0.0f);

    if (r == 0) out1[b] = fv + qv;
}

extern "C" void kernel_launch(void* const* d_in, const int* in_sizes, int n_in,
                              void* d_out, int out_size, void* d_ws, size_t ws_size,
                              hipStream_t stream)
{
    const float* x    = (const float*)d_in[0];
    const float* Wih  = (const float*)d_in[1];
    const float* Whh  = (const float*)d_in[2];
    const float* bih  = (const float*)d_in[3];
    const float* bhh  = (const float*)d_in[4];
    const float* Wa1  = (const float*)d_in[5];
    const float* ba1  = (const float*)d_in[6];
    const float* Wa2  = (const float*)d_in[7];
    const float* ba2  = (const float*)d_in[8];
    const float* Wa3  = (const float*)d_in[9];
    const float* ba3  = (const float*)d_in[10];
    const float* Wl1  = (const float*)d_in[11];
    const float* bl1  = (const float*)d_in[12];
    const float* Wl2  = (const float*)d_in[13];
    const float* bl2  = (const float*)d_in[14];
    const float* Wl3  = (const float*)d_in[15];
    const float* bl3  = (const float*)d_in[16];
    const float* Wihc = (const float*)d_in[17];
    const float* Whhc = (const float*)d_in[18];
    const float* bihc = (const float*)d_in[19];
    const float* bhhc = (const float*)d_in[20];
    const float* Wc1  = (const float*)d_in[21];
    const float* bc1  = (const float*)d_in[22];
    const float* Wc2  = (const float*)d_in[23];
    const float* bc2  = (const float*)d_in[24];
    const float* Wc3  = (const float*)d_in[25];
    const float* bc3  = (const float*)d_in[26];

    float* out0 = (float*)d_out;                    // p[:, -1, :]  (B*N)
    float* out1 = out0 + (size_t)Bn * Nn;           // q            (B)
    float* pbuf = (float*)d_ws;                     // B*6 floats

    dim3 g1(Bn / (16 * 4 * BT), Nn);                // 64 x 100 blocks, 4 waves each
    stage1_mfma<<<g1, 256, 0, stream>>>(x, Wih, Whh, bih, bhh,
                                        Wa1, ba1, Wa2, ba2, Wa3, ba3,
                                        out0, pbuf);
    stage2_split<<<Bn / 32, 256, 0, stream>>>(x, pbuf,
                                              Wl1, bl1, Wl2, bl2, Wl3, bl3,
                                              Wihc, Whhc, bihc, bhhc,
                                              Wc1, bc1, Wc2, bc2, Wc3, bc3,
                                              out1);
}

// Round 11
// 82.833 us; speedup vs baseline: 1.1367x; 1.1168x over previous
//
#include <hip/hip_runtime.h>

#define Bn 16384
#define Tn 2
#define Nn 100
#define BT 8   // batch tiles (of 16 items) per wave in stage1 (R11: 4->8, amortize block preamble)

typedef __attribute__((ext_vector_type(8))) short short8;   // 8 x bf16 MFMA frag
typedef __attribute__((ext_vector_type(4))) float f32x4;    // MFMA accum

__device__ __forceinline__ f32x4 mfma32(short8 a, short8 b, f32x4 c) {
    return __builtin_amdgcn_mfma_f32_16x16x32_bf16(a, b, c, 0, 0, 0);  // R3-verified
}

#define NEG_LOG2E  -1.44269504f
#define NEG_2LOG2E -2.88539008f

__device__ __forceinline__ float frcp(float v) { return __builtin_amdgcn_rcpf(v); }

__device__ __forceinline__ float fexp2(float v) {
#if __has_builtin(__builtin_amdgcn_exp2f)
    return __builtin_amdgcn_exp2f(v);
#else
    float r; asm("v_exp_f32 %0, %1" : "=v"(r) : "v"(v)); return r;
#endif
}
// sigma(c) where c already includes its bias (from the MFMA accumulator)
__device__ __forceinline__ float fsigc(float c) {
    return frcp(1.0f + fexp2(c * NEG_LOG2E));
}
// tanh(u) given s = -2*log2e*u  — clamp-free, no NaN path
__device__ __forceinline__ float ftanh2(float s) {
    return fmaf(frcp(1.0f + fexp2(s)), 2.0f, -1.0f);
}
// legacy forms for stage2 (proven)
__device__ __forceinline__ float fsig(float v) { return frcp(1.0f + __expf(-v)); }
__device__ __forceinline__ float ftanh(float v) {
    v = fminf(fmaxf(v, -15.0f), 15.0f);
    float e = __expf(-2.0f * v);
    return (1.0f - e) * frcp(1.0f + e);
}

// pack 2 f32 -> 2 bf16 (RNE), lo = a, hi = b
__device__ __forceinline__ unsigned pkbf(float a, float b) {
    unsigned r;
    asm("v_cvt_pk_bf16_f32 %0, %1, %2" : "=v"(r) : "v"(a), "v"(b));
    return r;
}

__device__ __forceinline__ short8 mk_frag(unsigned a, unsigned b, unsigned c, unsigned d) {
    union { unsigned u[4]; short8 s; } x;
    x.u[0] = a; x.u[1] = b; x.u[2] = c; x.u[3] = d;
    return x.s;
}

__device__ __forceinline__ unsigned shflu(unsigned v, int src) {
    return (unsigned)__shfl((int)v, src, 64);
}

// Build B-frag for a K=16 operand held in C-layout (R3-verified)
__device__ __forceinline__ short8 buildK16(unsigned hp0, unsigned hp1, int g, int m) {
    int s0 = ((32 * g + m) & 63);
    int s1 = ((32 * g + 16 + m) & 63);
    unsigned r0 = shflu(hp0, s0);
    unsigned r1 = shflu(hp1, s0);
    unsigned r2 = shflu(hp0, s1);
    unsigned r3 = shflu(hp1, s1);
    if (g >= 2) { r0 = 0; r1 = 0; r2 = 0; r3 = 0; }
    return mk_frag(r0, r1, r2, r3);
}

// A-frag for a row-major [16][16] weight: lane row = l&15, k = g*8+jj  (R3-verified)
__device__ __forceinline__ short8 loadA16(const float* __restrict__ w, int g, int jr) {
    if (g < 2) {
        const float4* q = (const float4*)(w + jr * 16 + g * 8);
        float4 q0 = q[0], q1 = q[1];
        return mk_frag(pkbf(q0.x, q0.y), pkbf(q0.z, q0.w),
                       pkbf(q1.x, q1.y), pkbf(q1.z, q1.w));
    }
    return mk_frag(0u, 0u, 0u, 0u);
}

// A-frag for a row-major [16][6] weight (K=6 at k0..5): only group 0 nonzero
__device__ __forceinline__ short8 loadA6(const float* __restrict__ w, int g, int jr) {
    if (g == 0) {
        const float2* q = (const float2*)(w + jr * 6);
        float2 a = q[0], b = q[1], c = q[2];
        return mk_frag(pkbf(a.x, a.y), pkbf(b.x, b.y), pkbf(c.x, c.y), 0u);
    }
    return mk_frag(0u, 0u, 0u, 0u);
}

// ============================ STAGE 1 (R10 + BT=8 preamble amortization) ============================
__global__ __launch_bounds__(256) void stage1_mfma(
    const float* __restrict__ x,
    const float* __restrict__ Wih, const float* __restrict__ Whh,
    const float* __restrict__ bih, const float* __restrict__ bhh,
    const float* __restrict__ Wa1, const float* __restrict__ ba1,
    const float* __restrict__ Wa2, const float* __restrict__ ba2,
    const float* __restrict__ Wa3, const float* __restrict__ ba3,
    float* __restrict__ out0, float* __restrict__ pbuf)
{
    const int n = blockIdx.y;
    const int l = threadIdx.x & 63;
    const int w = threadIdx.x >> 6;
    const int g = l >> 4;
    const int m = l & 15;
    const int wave_base = (blockIdx.x * 4 + w) * (16 * BT);

    short8 Aih0 = loadA6(Wih + n * 288 +  0 * 6, g, m);
    short8 Aih1 = loadA6(Wih + n * 288 + 16 * 6, g, m);
    short8 Aih2 = loadA6(Wih + n * 288 + 32 * 6, g, m);
    short8 Ahh0 = loadA16(Whh + n * 768 +   0, g, m);
    short8 Ahh1 = loadA16(Whh + n * 768 + 256, g, m);
    short8 Ahh2 = loadA16(Whh + n * 768 + 512, g, m);
    short8 Aa1f = loadA16(Wa1 + n * 256, g, m);
    short8 Aa2f = loadA16(Wa2 + n * 256, g, m);

    float4 bi0 = *(const float4*)(bih + n * 48 +  0 + g * 4);
    float4 bi1 = *(const float4*)(bih + n * 48 + 16 + g * 4);
    float4 bi2 = *(const float4*)(bih + n * 48 + 32 + g * 4);
    float4 bh0 = *(const float4*)(bhh + n * 48 +  0 + g * 4);
    float4 bh1 = *(const float4*)(bhh + n * 48 + 16 + g * 4);
    float4 bh2 = *(const float4*)(bhh + n * 48 + 32 + g * 4);
    float4 vb1 = *(const float4*)(ba1 + n * 16 + g * 4);
    float4 vb2 = *(const float4*)(ba2 + n * 16 + g * 4);
    float4 vw3 = *(const float4*)(Wa3 + n * 16 + g * 4);
    const float ba3n = ba3[n];
    const float* bh2a = (const float*)&bh2;
    const float* vw3a = (const float*)&vw3;

    // bias accumulators (f32x4) for MFMA C-operand init
    f32x4 BRS, BZS, BI2, BH2, VB1, VB2;
    {
        const float* a = (const float*)&bi0; const float* b = (const float*)&bh0;
        const float* c = (const float*)&bi1; const float* d = (const float*)&bh1;
        const float* e0 = (const float*)&bi2;
        const float* e1 = (const float*)&vb1; const float* e2 = (const float*)&vb2;
#pragma unroll
        for (int r = 0; r < 4; ++r) {
            BRS[r] = a[r] + b[r];
            BZS[r] = c[r] + d[r];
            BI2[r] = e0[r];
            BH2[r] = bh2a[r];
            VB1[r] = e1[r];
            VB2[r] = e2[r];
        }
    }

    // ---- x prefetch registers (tile 'it'); issued one tile ahead ----
    float2 p0, p1, p2, p3, p4, p5;
#define LOADX(BB) do { if (g == 0) { \
        const float* xr_ = x + (size_t)((BB) + m) * 1200 + n * 6; \
        p0 = *(const float2*)(xr_);       p1 = *(const float2*)(xr_ + 2); \
        p2 = *(const float2*)(xr_ + 4);   p3 = *(const float2*)(xr_ + 600); \
        p4 = *(const float2*)(xr_ + 602); p5 = *(const float2*)(xr_ + 604); } } while (0)

    LOADX(wave_base);   // tile 0

    for (int it = 0; it < BT; ++it) {
        const int bb = wave_base + it * 16;

        // dead-tile test (window [w0,w0+31] mod 200 fully discarded iff w0 <= 57)
        const unsigned w0 = (unsigned)(n * 168 + 2 * bb) % 200u;
        const bool live = (w0 > 57u);

        // pack current tile's x from prefetch regs (before they're overwritten)
        short8 Bx0 = mk_frag(0u,0u,0u,0u), Bx1 = mk_frag(0u,0u,0u,0u);
        if (live && g == 0) {
            Bx0 = mk_frag(pkbf(p0.x, p0.y), pkbf(p1.x, p1.y), pkbf(p2.x, p2.y), 0u);
            Bx1 = mk_frag(pkbf(p3.x, p3.y), pkbf(p4.x, p4.y), pkbf(p5.x, p5.y), 0u);
        }
        // issue next tile's loads; latency hides under this tile's body
        if (it + 1 < BT) LOADX(bb + 16);
        if (!live) continue;

        // ---- t0 gi MFMAs, then h-independent t1 gi MFMAs (fill matrix pipe) ----
        f32x4 Cr  = mfma32(Aih0, Bx0, BRS);
        f32x4 Cz  = mfma32(Aih1, Bx0, BZS);
        f32x4 Cn  = mfma32(Aih2, Bx0, BI2);
        f32x4 Cr1 = mfma32(Aih0, Bx1, BRS);
        f32x4 Cz1 = mfma32(Aih1, Bx1, BZS);
        f32x4 Cn1 = mfma32(Aih2, Bx1, BI2);

        // ---- t0 gates ----
        float h0[4];
#pragma unroll
        for (int r = 0; r < 4; ++r) {
            float rr = fsigc(Cr[r]);
            float zz = fsigc(Cz[r]);
            float s  = fmaf(rr, bh2a[r], Cn[r]) * NEG_2LOG2E;
            float nn = ftanh2(s);
            h0[r] = fmaf(-zz, nn, nn);          // (1-z)*n
        }
        unsigned hp0 = pkbf(h0[0], h0[1]), hp1 = pkbf(h0[2], h0[3]);
        short8 Bh0 = buildK16(hp0, hp1, g, m);

        // ---- t1 hidden-path MFMAs + t0 MLP layer-1 (independent of t1 gates) ----
        Cr1 = mfma32(Ahh0, Bh0, Cr1);
        Cz1 = mfma32(Ahh1, Bh0, Cz1);
        f32x4 Cn2 = mfma32(Ahh2, Bh0, BH2);
        f32x4 C1a = mfma32(Aa1f, Bh0, VB1);

        // ---- t1 gates ----
        float h1[4];
#pragma unroll
        for (int r = 0; r < 4; ++r) {
            float rr = fsigc(Cr1[r]);
            float zz = fsigc(Cz1[r]);
            float s  = fmaf(rr, Cn2[r], Cn1[r]) * NEG_2LOG2E;
            float nn = ftanh2(s);
            h1[r] = fmaf(zz, h0[r] - nn, nn);   // (1-z)*n + z*h0
        }
        short8 Bh1 = buildK16(pkbf(h1[0], h1[1]), pkbf(h1[2], h1[3]), g, m);

        // ---- DUAL MLP tail: two independent chains interleave ----
        f32x4 C1b = mfma32(Aa1f, Bh1, VB1);
        float a1a[4], a1b[4];
#pragma unroll
        for (int r = 0; r < 4; ++r) {
            a1a[r] = fmaxf(C1a[r], 0.0f);
            a1b[r] = fmaxf(C1b[r], 0.0f);
        }
        short8 Ba1a = buildK16(pkbf(a1a[0], a1a[1]), pkbf(a1a[2], a1a[3]), g, m);
        short8 Ba1b = buildK16(pkbf(a1b[0], a1b[1]), pkbf(a1b[2], a1b[3]), g, m);
        f32x4 C2a = mfma32(Aa2f, Ba1a, VB2);
        f32x4 C2b = mfma32(Aa2f, Ba1b, VB2);
        float pa = 0.0f, pb = 0.0f;
#pragma unroll
        for (int r = 0; r < 4; ++r) {
            pa += fmaxf(C2a[r], 0.0f) * vw3a[r];
            pb += fmaxf(C2b[r], 0.0f) * vw3a[r];
        }
        pa += __shfl_xor(pa, 16, 64); pb += __shfl_xor(pb, 16, 64);
        pa += __shfl_xor(pa, 32, 64); pb += __shfl_xor(pb, 32, 64);
        float o0 = fmaxf(pa + ba3n, 0.0f);
        float o1 = fmaxf(pb + ba3n, 0.0f);

        // ---- scatter through transpose/reshape: a[b,t,n] flat k0=n*B*T+b*T+t ----
        if (g == 0) {
            const unsigned b = (unsigned)(bb + m);
#pragma unroll
            for (int t = 0; t < 2; ++t) {
                unsigned k0 = (unsigned)n * (Bn * Tn) + b * 2u + (unsigned)t;
                unsigned b2 = k0 / 200u;
                unsigned rr = k0 - b2 * 200u;
                unsigned t2 = (rr >= 100u) ? 1u : 0u;
                unsigned n2 = rr - t2 * 100u;
                float v = (t == 0) ? o0 : o1;
                if (t2) out0[b2 * 100u + n2] = v;
                if (n2 == 99u)      pbuf[b2 * 6u + t2 * 3u + 0u] = v;
                else if (n2 == 89u) pbuf[b2 * 6u + t2 * 3u + 1u] = v;
                else if (n2 == 98u) pbuf[b2 * 6u + t2 * 3u + 2u] = v;
            }
        }
    }
#undef LOADX
}

// ============================ STAGE 2: 8 lanes per item, row-split (R7-proven) ============================
__global__ __launch_bounds__(256) void stage2_split(
    const float* __restrict__ x, const float* __restrict__ pbuf,
    const float* __restrict__ Wl1, const float* __restrict__ bl1,
    const float* __restrict__ Wl2, const float* __restrict__ bl2,
    const float* __restrict__ Wl3, const float* __restrict__ bl3,
    const float* __restrict__ Wihc, const float* __restrict__ Whhc,
    const float* __restrict__ bihc, const float* __restrict__ bhhc,
    const float* __restrict__ Wc1, const float* __restrict__ bc1,
    const float* __restrict__ Wc2, const float* __restrict__ bc2,
    const float* __restrict__ Wc3, const float* __restrict__ bc3,
    float* __restrict__ out1)
{
    const int tid = threadIdx.x;
    const int li  = tid >> 3;          // item in block, 0..31
    const int r   = tid & 7;           // lane role, 0..7
    const int b   = blockIdx.x * 32 + li;

    __shared__ float sf1[32][36];
    __shared__ float shc0[32][16];
    __shared__ float shc1[32][16];
    __shared__ float sv1[32][16];

    float u0[21], u1[21];
    {
        const float* xb = x + (size_t)b * 1200;
#pragma unroll
        for (int t = 0; t < 2; ++t) {
            float* u = t ? u1 : u0;
            const float* xt = xb + t * 600;
            float2 a0 = *(const float2*)(xt + 594), a1 = *(const float2*)(xt + 596),
                   a2 = *(const float2*)(xt + 598);                       // x99
            float2 b0 = *(const float2*)(xt + 534), b1 = *(const float2*)(xt + 536),
                   b2 = *(const float2*)(xt + 538);                       // x89
            float2 c0 = *(const float2*)(xt + 588), c1 = *(const float2*)(xt + 590),
                   c2 = *(const float2*)(xt + 592);                       // x98
            u[0]=a0.x; u[1]=a0.y; u[2]=a1.x; u[3]=a1.y; u[4]=a2.x; u[5]=a2.y;
            u[6]  = pbuf[b * 6 + t * 3 + 0];
            u[7]=b0.x; u[8]=b0.y; u[9]=b1.x; u[10]=b1.y; u[11]=b2.x; u[12]=b2.y;
            u[13] = pbuf[b * 6 + t * 3 + 1];
            u[14]=c0.x; u[15]=c0.y; u[16]=c1.x; u[17]=c1.y; u[18]=c2.x; u[19]=c2.y;
            u[20] = pbuf[b * 6 + t * 3 + 2];
        }
    }
    const int cmap[21] = {0,1,2,3,4,5,6, 7,8,9,10,11,12,13, 28,29,30,31,32,33,34};

#pragma unroll
    for (int k = 0; k < 5; ++k) {
        int j = r + 8 * k;
        if (j < 35) {
            const float* row = Wl1 + j * 35;
            float acc = bl1[j];
#pragma unroll
            for (int c = 0; c < 21; ++c) acc = fmaf(u1[c], row[cmap[c]], acc);
            sf1[li][j] = fmaxf(acc, 0.0f);
        }
    }
    __syncthreads();
    float f1[35];
    {
        const float4* p4 = (const float4*)&sf1[li][0];
#pragma unroll
        for (int q = 0; q < 8; ++q) {
            float4 v = p4[q];
            f1[4*q]=v.x; f1[4*q+1]=v.y; f1[4*q+2]=v.z; f1[4*q+3]=v.w;
        }
        f1[32]=sf1[li][32]; f1[33]=sf1[li][33]; f1[34]=sf1[li][34];
    }

    float fvp = 0.0f;
#pragma unroll
    for (int k = 0; k < 5; ++k) {
        int j = r + 8 * k;
        if (j < 35) {
            const float* row = Wl2 + j * 35;
            float acc = bl2[j];
#pragma unroll
            for (int kk = 0; kk < 35; ++kk) acc = fmaf(f1[kk], row[kk], acc);
            fvp += fmaxf(acc, 0.0f) * Wl3[j];
        }
    }
    fvp += __shfl_xor(fvp, 1, 64);
    fvp += __shfl_xor(fvp, 2, 64);
    fvp += __shfl_xor(fvp, 4, 64);
    const float fv = fmaxf(fvp + bl3[0], 0.0f);

    float g0[6], g1[6];
#pragma unroll
    for (int k = 0; k < 6; ++k) {
        int j = r + 8 * k;
        const float* row = Wihc + j * 35;
        float a0 = bihc[j], a1 = a0;
#pragma unroll
        for (int c = 0; c < 21; ++c) {
            float wv = row[cmap[c]];
            a0 = fmaf(u0[c], wv, a0);
            a1 = fmaf(u1[c], wv, a1);
        }
        g0[k] = a0; g1[k] = a1;
    }

    float bhr0 = bhhc[r],     bhz0 = bhhc[16 + r],  bhn0 = bhhc[32 + r];
    float bhr1 = bhhc[8 + r], bhz1 = bhhc[24 + r],  bhn1 = bhhc[40 + r];
    {
        float rr = fsig(g0[0] + bhr0);
        float zz = fsig(g0[2] + bhz0);
        float nn = ftanh(g0[4] + rr * bhn0);
        shc0[li][r] = (1.0f - zz) * nn;
        float rr2 = fsig(g0[1] + bhr1);
        float zz2 = fsig(g0[3] + bhz1);
        float nn2 = ftanh(g0[5] + rr2 * bhn1);
        shc0[li][r + 8] = (1.0f - zz2) * nn2;
    }
    __syncthreads();
    float hc0f[16];
    {
        const float4* p4 = (const float4*)&shc0[li][0];
#pragma unroll
        for (int q = 0; q < 4; ++q) {
            float4 v = p4[q];
            hc0f[4*q]=v.x; hc0f[4*q+1]=v.y; hc0f[4*q+2]=v.z; hc0f[4*q+3]=v.w;
        }
    }

    float gh[6];
#pragma unroll
    for (int k = 0; k < 6; ++k) {
        int j = r + 8 * k;
        const float4* wr = (const float4*)(Whhc + j * 16);
        float acc = bhhc[j];
#pragma unroll
        for (int q = 0; q < 4; ++q) {
            float4 v = wr[q];
            acc = fmaf(hc0f[4*q], v.x, acc);   acc = fmaf(hc0f[4*q+1], v.y, acc);
            acc = fmaf(hc0f[4*q+2], v.z, acc); acc = fmaf(hc0f[4*q+3], v.w, acc);
        }
        gh[k] = acc;
    }

    {
        float rr = fsig(g1[0] + gh[0]);
        float zz = fsig(g1[2] + gh[2]);
        float nn = ftanh(g1[4] + rr * gh[4]);
        shc1[li][r] = (1.0f - zz) * nn + zz * hc0f[r];
        float rr2 = fsig(g1[1] + gh[1]);
        float zz2 = fsig(g1[3] + gh[3]);
        float nn2 = ftanh(g1[5] + rr2 * gh[5]);
        shc1[li][r + 8] = (1.0f - zz2) * nn2 + zz2 * hc0f[r + 8];
    }
    __syncthreads();
    float hc1f[16];
    {
        const float4* p4 = (const float4*)&shc1[li][0];
#pragma unroll
        for (int q = 0; q < 4; ++q) {
            float4 v = p4[q];
            hc1f[4*q]=v.x; hc1f[4*q+1]=v.y; hc1f[4*q+2]=v.z; hc1f[4*q+3]=v.w;
        }
    }

#pragma unroll
    for (int k = 0; k < 2; ++k) {
        int j = r + 8 * k;
        const float4* wr = (const float4*)(Wc1 + j * 16);
        float acc = bc1[j];
#pragma unroll
        for (int q = 0; q < 4; ++q) {
            float4 v = wr[q];
            acc = fmaf(hc1f[4*q], v.x, acc);   acc = fmaf(hc1f[4*q+1], v.y, acc);
            acc = fmaf(hc1f[4*q+2], v.z, acc); acc = fmaf(hc1f[4*q+3], v.w, acc);
        }
        sv1[li][j] = fmaxf(acc, 0.0f);
    }
    __syncthreads();
    float v1f[16];
    {
        const float4* p4 = (const float4*)&sv1[li][0];
#pragma unroll
        for (int q = 0; q < 4; ++q) {
            float4 v = p4[q];
            v1f[4*q]=v.x; v1f[4*q+1]=v.y; v1f[4*q+2]=v.z; v1f[4*q+3]=v.w;
        }
    }

    float qvp = 0.0f;
#pragma unroll
    for (int k = 0; k < 2; ++k) {
        int j = r + 8 * k;
        const float4* wr = (const float4*)(Wc2 + j * 16);
        float acc = bc2[j];
#pragma unroll
        for (int q = 0; q < 4; ++q) {
            float4 v = wr[q];
            acc = fmaf(v1f[4*q], v.x, acc);   acc = fmaf(v1f[4*q+1], v.y, acc);
            acc = fmaf(v1f[4*q+2], v.z, acc); acc = fmaf(v1f[4*q+3], v.w, acc);
        }
        qvp += fmaxf(acc, 0.0f) * Wc3[j];
    }
    qvp += __shfl_xor(qvp, 1, 64);
    qvp += __shfl_xor(qvp, 2, 64);
    qvp += __shfl_xor(qvp, 4, 64);
    const float qv = fmaxf(qvp + bc3[0], 0.0f);

    if (r == 0) out1[b] = fv + qv;
}

extern "C" void kernel_launch(void* const* d_in, const int* in_sizes, int n_in,
                              void* d_out, int out_size, void* d_ws, size_t ws_size,
                              hipStream_t stream)
{
    const float* x    = (const float*)d_in[0];
    const float* Wih  = (const float*)d_in[1];
    const float* Whh  = (const float*)d_in[2];
    const float* bih  = (const float*)d_in[3];
    const float* bhh  = (const float*)d_in[4];
    const float* Wa1  = (const float*)d_in[5];
    const float* ba1  = (const float*)d_in[6];
    const float* Wa2  = (const float*)d_in[7];
    const float* ba2  = (const float*)d_in[8];
    const float* Wa3  = (const float*)d_in[9];
    const float* ba3  = (const float*)d_in[10];
    const float* Wl1  = (const float*)d_in[11];
    const float* bl1  = (const float*)d_in[12];
    const float* Wl2  = (const float*)d_in[13];
    const float* bl2  = (const float*)d_in[14];
    const float* Wl3  = (const float*)d_in[15];
    const float* bl3  = (const float*)d_in[16];
    const float* Wihc = (const float*)d_in[17];
    const float* Whhc = (const float*)d_in[18];
    const float* bihc = (const float*)d_in[19];
    const float* bhhc = (const float*)d_in[20];
    const float* Wc1  = (const float*)d_in[21];
    const float* bc1  = (const float*)d_in[22];
    const float* Wc2  = (const float*)d_in[23];
    const float* bc2  = (const float*)d_in[24];
    const float* Wc3  = (const float*)d_in[25];
    const float* bc3  = (const float*)d_in[26];

    float* out0 = (float*)d_out;                    // p[:, -1, :]  (B*N)
    float* out1 = out0 + (size_t)Bn * Nn;           // q            (B)
    float* pbuf = (float*)d_ws;                     // B*6 floats

    dim3 g1(Bn / (16 * 4 * BT), Nn);                // 32 x 100 blocks, 4 waves each
    stage1_mfma<<<g1, 256, 0, stream>>>(x, Wih, Whh, bih, bhh,
                                        Wa1, ba1, Wa2, ba2, Wa3, ba3,
                                        out0, pbuf);
    stage2_split<<<Bn / 32, 256, 0, stream>>>(x, pbuf,
                                              Wl1, bl1, Wl2, bl2, Wl3, bl3,
                                              Wihc, Whhc, bihc, bhhc,
                                              Wc1, bc1, Wc2, bc2, Wc3, bc3,
                                              out1);
}